// Round 4
// baseline (519.062 us; speedup 1.0000x reference)
//
#include <hip/hip_runtime.h>

// Cost volume: out[b,d,h,w] = (1/C) * sum_c L[b,c,h,w] * R[b,c,h,w-d], zero for w<d.
// B=8, C=128, H=96, W=320, D=48, fp32.
//
// Round 4: attack wave starvation (3.75 waves/SIMD, VALUBusy 25%).
//  - C-split-2: 640 threads/block; thread pairs (t, t+320) share one 4w x 12d tile,
//    each accumulates half the channels (cc 0-3 vs 4-7 of each staged chunk).
//    Total waves double: 7680 -> 5/SIMD (2 blocks/CU at ~90 VGPR).
//  - L no longer staged in LDS: read direct from global (L1/L2-cached, 4x reuse).
//    Cuts DS instructions ~23% (DS was the busiest pipe at ~50-70%).
//  - Rs triple-buffered: prefetch distance = 2 chunks (~800+ cyc) >= HBM latency,
//    even though per-chunk compute halved to ~400 cyc.
//  - Epilogue: B-half stages its 48 partials via conflict-free LDS layout
//    ([6][320] float4, lane-contiguous), A-half adds, scales by 1/128, stores.

constexpr int Cn = 128, Hn = 96, Wn = 320, Dn = 48;
constexpr int CC = 8;                 // channels staged per chunk
constexpr int RW = Wn + 48;           // padded R row = 368 floats
constexpr int NCH = Cn / CC;          // 16 chunks
constexpr int NBUF = 3;               // triple buffer
constexpr size_t planeHW = (size_t)Hn * Wn;   // 30720

__global__ __launch_bounds__(640, 5)
void costvol_kernel(const float* __restrict__ L, const float* __restrict__ R,
                    float* __restrict__ out) {
  __shared__ float Rs[NBUF][CC][RW];   // 35328 B -> LDS allows 4 blocks; VGPR caps 2

  const int bh = blockIdx.x;
  const int b = bh / Hn, h = bh % Hn;
  const int tid = threadIdx.x;
  const int g = (tid >= 320) ? 1 : 0;  // channel-half
  const int t5 = tid - g * 320;        // tile index 0..319

  // Zero the 48-float left pads of all three buffers (written once).
  for (int i = tid; i < NBUF * CC * 48; i += 640) {
    const int bu = i / (CC * 48), rem = i % (CC * 48);
    Rs[bu][rem / 48][rem % 48] = 0.f;
  }

  const int wg = t5 % 80, dg = t5 / 80;      // 80 w-groups x 4 d-groups
  const int w0 = wg * 4, d0 = dg * 12;
  const int p0 = w0 - d0 + 36;               // aligned (mod 4) window base in Rs
  const int ccb = g * 4;                     // this thread's channel sub-range

  float acc[12][4];
#pragma unroll
  for (int k = 0; k < 12; ++k)
#pragma unroll
    for (int i = 0; i < 4; ++i) acc[k][i] = 0.f;

  const size_t baseBH = (size_t)b * Cn * planeHW + (size_t)h * Wn;
  const size_t cstep = (size_t)CC * planeHW;

  // R staging map: 640 threads x 1 float4 = 8 rows x 320 floats. Coalesced.
  const int srow = tid / 80;                 // 0..7
  const int scol = (tid % 80) * 4;
  const float* Rp = R + baseBH + (size_t)srow * planeHW + scol;

  // L direct-from-global base for this thread's channel half.
  const float* Lg = L + baseBH + (size_t)ccb * planeHW + w0;

  auto compute = [&](int buf, int tc) {
    const float* Lc = Lg + (size_t)tc * cstep;
#pragma unroll
    for (int cc = 0; cc < 4; ++cc) {
      const float4 lv = *(const float4*)(Lc + (size_t)cc * planeHW);
      const float* rrow = &Rs[buf][ccb + cc][0];
      float q[16];
#pragma unroll
      for (int tt = 0; tt < 4; ++tt) {
        const float4 qq = *(const float4*)&rrow[p0 + 4 * tt];
        q[4 * tt + 0] = qq.x; q[4 * tt + 1] = qq.y;
        q[4 * tt + 2] = qq.z; q[4 * tt + 3] = qq.w;
      }
      const float lw[4] = {lv.x, lv.y, lv.z, lv.w};
      // d = d0+k, w = w0+i needs R[w-d] at Rs col w0+i-d0-k+48 = p0 + (i-k+12)
#pragma unroll
      for (int k = 0; k < 12; ++k)
#pragma unroll
        for (int i = 0; i < 4; ++i)
          acc[k][i] += lw[i] * q[i - k + 12];
    }
  };

  // ---- prologue: chunk 0 -> Rs[0]; chunk 1 -> rA ----
  float4 r0v = *(const float4*)Rp; Rp += cstep;
  *(float4*)&Rs[0][srow][48 + scol] = r0v;
  float4 rA = *(const float4*)Rp; Rp += cstep;
  float4 rB;
  __syncthreads();

  // Steady state per part t: write chunk t+1 (regs) -> Rs[(t+1)%3], barrier,
  // issue chunk t+2 loads, compute Rs[t%3]. Loads issued 2 parts before their
  // ds_write -> ~2 chunks of compute hide HBM latency. Unrolled x2 for the
  // rA/rB ping-pong (no reg-copy of an in-flight load).
  for (int t = 0; t < NCH; t += 2) {
    // chunk t
    if (t + 1 < NCH) {
      *(float4*)&Rs[(t + 1) % 3][srow][48 + scol] = rA;
      __syncthreads();
    }
    if (t + 2 < NCH) { rB = *(const float4*)Rp; Rp += cstep; }
    compute(t % 3, t);
    // chunk t+1
    if (t + 1 < NCH) {
      if (t + 2 < NCH) {
        *(float4*)&Rs[(t + 2) % 3][srow][48 + scol] = rB;
        __syncthreads();
      }
      if (t + 3 < NCH) { rA = *(const float4*)Rp; Rp += cstep; }
      compute((t + 1) % 3, t + 1);
    }
  }

  // ---- combine the two channel halves and store ----
  __syncthreads();                       // all compute reads of Rs done
  float4* xbuf = (float4*)&Rs[0][0][0];  // reuse: need 6*320*16 B = 30720 <= 35328
  const size_t obase = ((size_t)b * Dn + d0) * planeHW + (size_t)h * Wn + w0;

#pragma unroll
  for (int halfd = 0; halfd < 2; ++halfd) {
    if (g == 1) {
#pragma unroll
      for (int k2 = 0; k2 < 6; ++k2) {
        const int k = halfd * 6 + k2;
        float4 v;
        v.x = acc[k][0]; v.y = acc[k][1]; v.z = acc[k][2]; v.w = acc[k][3];
        xbuf[k2 * 320 + t5] = v;         // lane-contiguous: conflict-free
      }
    }
    __syncthreads();
    if (g == 0) {
#pragma unroll
      for (int k2 = 0; k2 < 6; ++k2) {
        const int k = halfd * 6 + k2;
        const float4 v = xbuf[k2 * 320 + t5];
        float4 o;
        o.x = (acc[k][0] + v.x) * (1.f / 128.f);
        o.y = (acc[k][1] + v.y) * (1.f / 128.f);
        o.z = (acc[k][2] + v.z) * (1.f / 128.f);
        o.w = (acc[k][3] + v.w) * (1.f / 128.f);
        *(float4*)(out + obase + (size_t)k * planeHW) = o;
      }
    }
    __syncthreads();
  }
}

extern "C" void kernel_launch(void* const* d_in, const int* in_sizes, int n_in,
                              void* d_out, int out_size, void* d_ws, size_t ws_size,
                              hipStream_t stream) {
  const float* Lf = (const float*)d_in[0];
  const float* Rf = (const float*)d_in[1];
  float* outp = (float*)d_out;
  const int B = 8;
  costvol_kernel<<<dim3(B * Hn), dim3(640), 0, stream>>>(Lf, Rf, outp);
}

// Round 5
// 97.900 us; speedup vs baseline: 5.3019x; 5.3019x over previous
//
#include <hip/hip_runtime.h>

// Cost volume: out[b,d,h,w] = (1/C) * sum_c L[b,c,h,w] * R[b,c,h,w-d], zero for w<d.
// B=8, C=128, H=96, W=320, D=48, fp32.
//
// Round 5: round-4 structure (C-split-2, 640 thr, L direct-from-global, triple-buffer Rs)
// with the spill bug fixed:
//  - __launch_bounds__(640) ONLY. Round 4's (640,5) min-waves arg forced VGPR=48 and
//    spilled acc+q to scratch (WRITE_SIZE 1.28 GB, 5x regression).
//  - compute as __forceinline__ function (no lambda capture).

constexpr int Cn = 128, Hn = 96, Wn = 320, Dn = 48;
constexpr int CC = 8;                 // channels staged per chunk
constexpr int RW = Wn + 48;           // padded R row = 368 floats
constexpr int NCH = Cn / CC;          // 16 chunks
constexpr int NBUF = 3;               // triple buffer
constexpr size_t planeHW = (size_t)Hn * Wn;   // 30720

__device__ __forceinline__
void compute_chunk(const float* __restrict__ rs,   // &Rs[buf][0][0], this thread's ccb applied by caller? no: base
                   int ccb, int p0,
                   const float* __restrict__ Lc,   // L ptr at (chunk, ccb, h, w0)
                   float acc[12][4]) {
#pragma unroll
  for (int cc = 0; cc < 4; ++cc) {
    const float4 lv = *(const float4*)(Lc + (size_t)cc * planeHW);
    const float* rrow = rs + (size_t)(ccb + cc) * RW;
    float q[16];
#pragma unroll
    for (int tt = 0; tt < 4; ++tt) {
      const float4 qq = *(const float4*)&rrow[p0 + 4 * tt];
      q[4 * tt + 0] = qq.x; q[4 * tt + 1] = qq.y;
      q[4 * tt + 2] = qq.z; q[4 * tt + 3] = qq.w;
    }
    const float lw[4] = {lv.x, lv.y, lv.z, lv.w};
    // d = d0+k, w = w0+i needs R[w-d] at Rs col w0+i-d0-k+48 = p0 + (i-k+12)
#pragma unroll
    for (int k = 0; k < 12; ++k)
#pragma unroll
      for (int i = 0; i < 4; ++i)
        acc[k][i] += lw[i] * q[i - k + 12];
  }
}

__global__ __launch_bounds__(640)
void costvol_kernel(const float* __restrict__ L, const float* __restrict__ R,
                    float* __restrict__ out) {
  __shared__ float Rs[NBUF][CC][RW];   // 35328 B -> 3 blocks/CU (wave-cap), grid = 3/CU

  const int bh = blockIdx.x;
  const int b = bh / Hn, h = bh % Hn;
  const int tid = threadIdx.x;
  const int g = (tid >= 320) ? 1 : 0;  // channel-half
  const int t5 = tid - g * 320;        // tile index 0..319

  // Zero the 48-float left pads of all three buffers (written once).
  for (int i = tid; i < NBUF * CC * 48; i += 640) {
    const int bu = i / (CC * 48), rem = i % (CC * 48);
    Rs[bu][rem / 48][rem % 48] = 0.f;
  }

  const int wg = t5 % 80, dg = t5 / 80;      // 80 w-groups x 4 d-groups
  const int w0 = wg * 4, d0 = dg * 12;
  const int p0 = w0 - d0 + 36;               // aligned (mod 4) window base in Rs
  const int ccb = g * 4;                     // this thread's channel sub-range

  float acc[12][4];
#pragma unroll
  for (int k = 0; k < 12; ++k)
#pragma unroll
    for (int i = 0; i < 4; ++i) acc[k][i] = 0.f;

  const size_t baseBH = (size_t)b * Cn * planeHW + (size_t)h * Wn;
  const size_t cstep = (size_t)CC * planeHW;

  // R staging map: 640 threads x 1 float4 = 8 rows x 320 floats. Coalesced.
  const int srow = tid / 80;                 // 0..7
  const int scol = (tid % 80) * 4;
  const float* Rp = R + baseBH + (size_t)srow * planeHW + scol;

  // L direct-from-global base for this thread's channel half.
  const float* Lg = L + baseBH + (size_t)ccb * planeHW + w0;

  // ---- prologue: chunk 0 -> Rs[0]; chunk 1 -> rA ----
  float4 r0v = *(const float4*)Rp; Rp += cstep;
  *(float4*)&Rs[0][srow][48 + scol] = r0v;
  float4 rA = *(const float4*)Rp; Rp += cstep;
  float4 rB;
  __syncthreads();

  // Steady state per chunk t: ds_write chunk t+1 (in regs) -> Rs[(t+1)%3], barrier,
  // issue chunk t+2 global loads, compute Rs[t%3]. Loads issued ~2 chunks of
  // compute before their use. Unrolled x2 for the rA/rB ping-pong.
  for (int t = 0; t < NCH; t += 2) {
    // chunk t
    if (t + 1 < NCH) {
      *(float4*)&Rs[(t + 1) % 3][srow][48 + scol] = rA;
      __syncthreads();
    }
    if (t + 2 < NCH) { rB = *(const float4*)Rp; Rp += cstep; }
    compute_chunk(&Rs[t % 3][0][0], ccb, p0, Lg + (size_t)t * cstep, acc);
    // chunk t+1
    if (t + 1 < NCH) {
      if (t + 2 < NCH) {
        *(float4*)&Rs[(t + 2) % 3][srow][48 + scol] = rB;
        __syncthreads();
      }
      if (t + 3 < NCH) { rA = *(const float4*)Rp; Rp += cstep; }
      compute_chunk(&Rs[(t + 1) % 3][0][0], ccb, p0, Lg + (size_t)(t + 1) * cstep, acc);
    }
  }

  // ---- combine the two channel halves and store ----
  __syncthreads();                       // all compute reads of Rs done
  float4* xbuf = (float4*)&Rs[0][0][0];  // reuse: 6*320*16 B = 30720 <= 35328
  const size_t obase = ((size_t)b * Dn + d0) * planeHW + (size_t)h * Wn + w0;

#pragma unroll
  for (int halfd = 0; halfd < 2; ++halfd) {
    if (g == 1) {
#pragma unroll
      for (int k2 = 0; k2 < 6; ++k2) {
        const int k = halfd * 6 + k2;
        float4 v;
        v.x = acc[k][0]; v.y = acc[k][1]; v.z = acc[k][2]; v.w = acc[k][3];
        xbuf[k2 * 320 + t5] = v;         // lane-contiguous: conflict-free
      }
    }
    __syncthreads();
    if (g == 0) {
#pragma unroll
      for (int k2 = 0; k2 < 6; ++k2) {
        const int k = halfd * 6 + k2;
        const float4 v = xbuf[k2 * 320 + t5];
        float4 o;
        o.x = (acc[k][0] + v.x) * (1.f / 128.f);
        o.y = (acc[k][1] + v.y) * (1.f / 128.f);
        o.z = (acc[k][2] + v.z) * (1.f / 128.f);
        o.w = (acc[k][3] + v.w) * (1.f / 128.f);
        *(float4*)(out + obase + (size_t)k * planeHW) = o;
      }
    }
    __syncthreads();
  }
}

extern "C" void kernel_launch(void* const* d_in, const int* in_sizes, int n_in,
                              void* d_out, int out_size, void* d_ws, size_t ws_size,
                              hipStream_t stream) {
  const float* Lf = (const float*)d_in[0];
  const float* Rf = (const float*)d_in[1];
  float* outp = (float*)d_out;
  const int B = 8;
  costvol_kernel<<<dim3(B * Hn), dim3(640), 0, stream>>>(Lf, Rf, outp);
}